// Round 14
// baseline (1189.184 us; speedup 1.0000x reference)
//
#include <hip/hip_runtime.h>
#include <hip/hip_fp16.h>
#include <math.h>

#define D 128
#define PF 8

typedef _Float16 f16x8 __attribute__((ext_vector_type(8)));
typedef _Float16 f16x2 __attribute__((ext_vector_type(2)));
typedef float f32x4_t __attribute__((ext_vector_type(4)));

static __device__ __forceinline__ f16x2 h2v(__half2 h) {
    union { __half2 h; f16x2 v; } u; u.h = h; return u.v;
}
static __device__ __forceinline__ __half2 v2h(f16x2 v) {
    union { f16x2 v; __half2 h; } u; u.v = v; return u.h;
}

// ---------------- CSR build (once per call; edge_index is layer-invariant) ----------------

__global__ void hist_kernel(const int* __restrict__ edge_index, int* __restrict__ deg, int E) {
    int e = blockIdx.x * blockDim.x + threadIdx.x;
    if (e >= E) return;
    atomicAdd(&deg[edge_index[E + e]], 1);
}

__global__ void scanA_kernel(const int* __restrict__ deg, int* __restrict__ bsum, int n) {
    __shared__ int red[256];
    int b = blockIdx.x, t = threadIdx.x;
    int base = b * 1024 + t * 4;
    int s = 0;
#pragma unroll
    for (int j = 0; j < 4; ++j)
        if (base + j < n) s += deg[base + j];
    red[t] = s;
    __syncthreads();
    for (int off = 128; off > 0; off >>= 1) {
        if (t < off) red[t] += red[t + off];
        __syncthreads();
    }
    if (t == 0) bsum[b] = red[0];
}

__global__ void scanB_kernel(int* __restrict__ bsum, int nb) {
    __shared__ int sh[256];
    int t = threadIdx.x;
    sh[t] = (t < nb) ? bsum[t] : 0;
    __syncthreads();
    for (int off = 1; off < 256; off <<= 1) {
        int v = (t >= off) ? sh[t - off] : 0;
        __syncthreads();
        sh[t] += v;
        __syncthreads();
    }
    if (t < nb) bsum[t] = (t == 0) ? 0 : sh[t - 1];
}

// writes row_start AND cursor (saves a d2d memcpy dispatch)
__global__ void scanC_kernel(const int* __restrict__ deg, const int* __restrict__ boff,
                             int* __restrict__ row_start, int* __restrict__ cursor, int n) {
    __shared__ int sh[256];
    int b = blockIdx.x, t = threadIdx.x;
    int base = b * 1024 + t * 4;
    int v[4];
#pragma unroll
    for (int j = 0; j < 4; ++j) v[j] = (base + j < n) ? deg[base + j] : 0;
    int p[4];
    p[0] = 0; p[1] = v[0]; p[2] = v[0] + v[1]; p[3] = v[0] + v[1] + v[2];
    int s = p[3] + v[3];
    sh[t] = s;
    __syncthreads();
    for (int off = 1; off < 256; off <<= 1) {
        int x = (t >= off) ? sh[t - off] : 0;
        __syncthreads();
        sh[t] += x;
        __syncthreads();
    }
    int off0 = boff[b] + sh[t] - s;
#pragma unroll
    for (int j = 0; j < 4; ++j)
        if (base + j < n) {
            row_start[base + j] = off0 + p[j];
            cursor[base + j] = off0 + p[j];
        }
    if (base <= n - 1 && n - 1 < base + 4) row_start[n] = off0 + s;
}

__global__ void scatter_kernel(const int* __restrict__ edge_index, const int* __restrict__ edge_attr,
                               int* __restrict__ cursor, int2* __restrict__ csr, int E) {
    int e = blockIdx.x * blockDim.x + threadIdx.x;
    if (e >= E) return;
    int src = edge_index[e];
    int dst = edge_index[E + e];
    int pos = atomicAdd(&cursor[dst], 1);
    int a0 = edge_attr[e * 3], a1 = edge_attr[e * 3 + 1], a2 = edge_attr[e * 3 + 2];
    csr[pos] = make_int2(src, a0 | (a1 << 3) | (a2 << 6));
}

// fused small setup: ev table (512 combos, half2) + Wt f16 transpose + gstart
__global__ void misc_build_kernel(const float* __restrict__ bond_emb, __half2* __restrict__ evt,
                                  const float* __restrict__ conv_w, _Float16* __restrict__ wt,
                                  int wtTotal, const int* __restrict__ batch,
                                  int* __restrict__ gstart, int N, int G) {
    int idx = blockIdx.x * blockDim.x + threadIdx.x;
    if (idx < 512 * 64) {
        int combo = idx >> 6, j = idx & 63;
        int d0 = 2 * j;
        float ex = bond_emb[(combo & 7) * D + d0] +
                   bond_emb[(8 + ((combo >> 3) & 7)) * D + d0] +
                   bond_emb[(16 + ((combo >> 6) & 7)) * D + d0];
        float ey = bond_emb[(combo & 7) * D + d0 + 1] +
                   bond_emb[(8 + ((combo >> 3) & 7)) * D + d0 + 1] +
                   bond_emb[(16 + ((combo >> 6) & 7)) * D + d0 + 1];
        evt[idx] = __floats2half2_rn(ex, ey);
        return;
    }
    int widx = idx - 512 * 64;
    if (widx < wtTotal) {
        int l = widx >> 14;
        int rem = widx & 16383;
        int n = rem >> 7, k = rem & 127;
        wt[widx] = (_Float16)conv_w[(l << 14) + k * 128 + n];
        return;
    }
    int n = widx - wtTotal;
    if (n >= N) return;
    if (n == 0) {
        for (int g = 0; g <= batch[0]; ++g) gstart[g] = 0;
    } else {
        int b0 = batch[n - 1], b1 = batch[n];
        for (int g = b0 + 1; g <= b1; ++g) gstart[g] = n;
    }
    if (n == N - 1) {
        for (int g = batch[N - 1] + 1; g <= G; ++g) gstart[g] = N;
    }
}

// ---------------- model kernels ----------------

// node state is f16-only
__global__ void atom_embed_kernel(const int* __restrict__ x,
                                  const float* __restrict__ atom_emb,
                                  _Float16* __restrict__ h16, int N) {
    long long idx = (long long)blockIdx.x * blockDim.x + threadIdx.x;
    if (idx >= (long long)N * D) return;
    int n = (int)(idx >> 7);
    int d = (int)(idx & 127);
    float acc = 0.f;
#pragma unroll
    for (int f = 0; f < 9; ++f) {
        int v = x[n * 9 + f];
        acc += atom_emb[(long long)(f * 64 + v) * D + d];
    }
    h16[idx] = (_Float16)acc;
}

// reduce per-tile column partials (layout partial[tile*256 + slot]) -> folded BN coeffs
__global__ void bn_reduce_finalize_kernel(const float* __restrict__ partial, int nb,
                                          const float* __restrict__ gamma,
                                          const float* __restrict__ bnbeta, float invN,
                                          float* __restrict__ aArr, float* __restrict__ bArr) {
    __shared__ float r1[256], r2[256];
    int d = blockIdx.x, t = threadIdx.x;
    float a1 = 0.f, a2 = 0.f;
    for (int i = t; i < nb; i += 256) {
        a1 += partial[(long long)i * 256 + d];
        a2 += partial[(long long)i * 256 + 128 + d];
    }
    r1[t] = a1; r2[t] = a2;
    __syncthreads();
    for (int off = 128; off > 0; off >>= 1) {
        if (t < off) { r1[t] += r1[t + off]; r2[t] += r2[t + off]; }
        __syncthreads();
    }
    if (t == 0) {
        float mean = r1[0] * invN;
        float var = r2[0] * invN - mean * mean;
        float a = rsqrtf(var + 1e-5f) * gamma[d];
        aArr[d] = a;
        bArr[d] = bnbeta[d] - mean * a;
    }
}

// Per-layer fused, BARRIER-FREE, 8-ROW WAVE TILES [R13 lesson: wave count is the
// controlling resource — 16-row waves halved TLP and regressed]: each wave owns an
// 8-row tile end-to-end. Agg (f16 gathers, packed-f16 BN, 8-deep pipeline,
// double-buffered csr chunks [R10: FIFO vmcnt], register self rows, write-only close)
// -> private 16-row LDS region (rows 8-15 zero-filled) -> zero-padded 16x16 MFMA
// (only rows 0-7 stored; padding can't corrupt them) -> f16 out + shfl BN-stats.
// NO __syncthreads. segment-max skipped (softmax shift-invariant, msg bounded).
// NOTE (R9): NO global work-stealing counters on multi-XCD CDNA.
__global__ __launch_bounds__(128, 8) void fused_layer_kernel(
        const __half2* __restrict__ h16c,
        const float* __restrict__ aArr, const float* __restrict__ bArr, int applyBN,
        const float* __restrict__ ts, int l,
        const int* __restrict__ row_start, const int2* __restrict__ csr,
        const __half2* __restrict__ evt,
        const _Float16* __restrict__ wt, const float* __restrict__ bias,
        int residual, _Float16* __restrict__ h16out,
        float* __restrict__ partial, int nTiles, int N) {
    // 2 wave regions x 16 rows x 136 halves (pad 8) = 8704 B; rows 8-15 zeroed
    __shared__ __align__(16) char smem[8704];
    _Float16* yh = (_Float16*)smem;
    __half2* tile2 = (__half2*)smem;  // half2 view: row stride 68

    int t = threadIdx.x;
    int wave = t >> 6;
    int lane = t & 63;
    int tile = blockIdx.x * 2 + wave;
    if (tile >= nTiles) return;  // wave-uniform; no barriers anywhere
    int row0 = tile * 8;
    float tsl = ts[l];

    f16x2 zerov = (f16x2)(_Float16)0;
    f16x2 bnA2 = zerov, bnB2 = zerov;
    if (applyBN) {
        float2 af = ((const float2*)aArr)[lane];
        float2 bf = ((const float2*)bArr)[lane];
        bnA2[0] = (_Float16)af.x; bnA2[1] = (_Float16)af.y;
        bnB2[0] = (_Float16)bf.x; bnB2[1] = (_Float16)bf.y;
    }
    __half2 zero2 = v2h(zerov);

    // zero-fill MFMA padding rows 8-15 of this wave's region
#pragma unroll
    for (int i = 8; i < 16; ++i) tile2[(wave * 16 + i) * 68 + lane] = zero2;

    // row boundaries: lanes 0..8 hold row_start[row0+i]
    int rsv = row_start[min(row0 + min(lane, 8), N)];

    // 8 self-row gathers, register-resident (issued before readlane: FIFO waits only rsv)
    __half2 hsv0 = zero2, hsv1 = zero2, hsv2 = zero2, hsv3 = zero2;
    __half2 hsv4 = zero2, hsv5 = zero2, hsv6 = zero2, hsv7 = zero2;
    if (row0 + 0 < N) hsv0 = h16c[(size_t)(row0 + 0) * 64 + lane];
    if (row0 + 1 < N) hsv1 = h16c[(size_t)(row0 + 1) * 64 + lane];
    if (row0 + 2 < N) hsv2 = h16c[(size_t)(row0 + 2) * 64 + lane];
    if (row0 + 3 < N) hsv3 = h16c[(size_t)(row0 + 3) * 64 + lane];
    if (row0 + 4 < N) hsv4 = h16c[(size_t)(row0 + 4) * 64 + lane];
    if (row0 + 5 < N) hsv5 = h16c[(size_t)(row0 + 5) * 64 + lane];
    if (row0 + 6 < N) hsv6 = h16c[(size_t)(row0 + 6) * 64 + lane];
    if (row0 + 7 < N) hsv7 = h16c[(size_t)(row0 + 7) * 64 + lane];

    int s0 = __builtin_amdgcn_readlane(rsv, 0);
    int s1 = __builtin_amdgcn_readlane(rsv, 8);

    // double-buffered csr chunks: eaCur active, eaNxt in flight
    int c0 = s0;
    int2 eaCur = make_int2(0, 0), eaNxt = make_int2(0, 0);
    if (c0 + lane < s1) eaCur = csr[c0 + lane];
    if (c0 + 64 + lane < s1) eaNxt = csr[c0 + 64 + lane];

    __half2 hvS[PF], evS[PF];
#pragma unroll
    for (int k = 0; k < PF; ++k) {
        int pp = s0 + k;
        if (pp < s1) {  // q = k < 64: always chunk 0
            int srcp = __builtin_amdgcn_readlane(eaCur.x, k);
            int cbp = __builtin_amdgcn_readlane(eaCur.y, k);
            hvS[k] = h16c[(size_t)srcp * 64 + lane];
            evS[k] = evt[(size_t)cbp * 64 + lane];
        }
    }

    float accwx = 0.f, accwy = 0.f, accmx = 0.f, accmy = 0.f;
    int cur = 0;
    int nend = __builtin_amdgcn_readlane(rsv, 1);

#define CLOSE_ROW()                                                           \
    {                                                                         \
        __half2 hh;                                                           \
        switch (cur) {                                                        \
            case 0: hh = hsv0; break; case 1: hh = hsv1; break;               \
            case 2: hh = hsv2; break; case 3: hh = hsv3; break;               \
            case 4: hh = hsv4; break; case 5: hh = hsv5; break;               \
            case 6: hh = hsv6; break; default: hh = hsv7; break;              \
        }                                                                     \
        f16x2 hvv = h2v(hh);                                                  \
        if (applyBN)                                                          \
            hvv = __builtin_elementwise_max(hvv * bnA2 + bnB2, zerov);        \
        float2 yy;                                                            \
        yy.x = (float)hvv[0] + accmx / (accwx + 1e-16f);                      \
        yy.y = (float)hvv[1] + accmy / (accwy + 1e-16f);                      \
        tile2[(wave * 16 + cur) * 68 + lane] = __floats2half2_rn(yy.x, yy.y); \
        accwx = accwy = accmx = accmy = 0.f;                                  \
        cur++;                                                                \
        nend = __builtin_amdgcn_readlane(rsv, min(cur + 1, 8));               \
    }

    while (cur < 8 && nend == s0) CLOSE_ROW();  // leading empty rows

    int total = s1 - s0;
    for (int it = 0; it < total; it += PF) {
#pragma unroll
        for (int k = 0; k < PF; ++k) {
            int p = s0 + it + k;
            if (p < s1) {
                f16x2 hv2 = h2v(hvS[k]);
                if (applyBN)
                    hv2 = __builtin_elementwise_max(hv2 * bnA2 + bnB2, zerov);
                f16x2 m2 = __builtin_elementwise_max(hv2 + h2v(evS[k]), zerov);
                float mx = (float)m2[0] + 1e-7f;
                float my = (float)m2[1] + 1e-7f;
                float wx = __expf(mx * tsl);
                float wy = __expf(my * tsl);
                accwx += wx; accmx = fmaf(wx, mx, accmx);
                accwy += wy; accmy = fmaf(wy, my, accmy);
                int pp = p + PF;
                if (pp < s1) {
                    if (pp >= c0 + 64) {  // rollover: eaNxt loaded ~64 edges ago, no drain
                        c0 += 64;
                        eaCur = eaNxt;
                        eaNxt = make_int2(0, 0);
                        if (c0 + 64 + lane < s1) eaNxt = csr[c0 + 64 + lane];
                    }
                    int q = pp - c0;
                    int srcp = __builtin_amdgcn_readlane(eaCur.x, q);
                    int cbp = __builtin_amdgcn_readlane(eaCur.y, q);
                    hvS[k] = h16c[(size_t)srcp * 64 + lane];
                    evS[k] = evt[(size_t)cbp * 64 + lane];
                }
                while (cur < 8 && nend == p + 1) CLOSE_ROW();
            }
        }
    }
#undef CLOSE_ROW

    // ---- per-wave zero-padded MFMA: rows 0-7 valid, 8 col-tiles of 16 cols ----
    // (no barrier: LDS region is wave-private; compiler inserts lgkmcnt waits)
    int ln = lane & 15;
    int quad = lane >> 4;
    const _Float16* h16in = (const _Float16*)h16c;
    const _Float16* ap = yh + (wave * 16 + ln) * 136 + quad * 8;

    float csv[8], cqv[8];
#pragma unroll
    for (int ct = 0; ct < 8; ++ct) {
        int colg = ct * 16 + ln;
        const _Float16* bp = wt + (size_t)colg * 128 + quad * 8;
        f32x4_t c = {0.f, 0.f, 0.f, 0.f};
#pragma unroll
        for (int kk = 0; kk < 4; ++kk) {
            f16x8 av = *(const f16x8*)(ap + kk * 32);
            f16x8 bv = *(const f16x8*)(bp + kk * 32);
            c = __builtin_amdgcn_mfma_f32_16x16x32_f16(av, bv, c, 0, 0, 0);
        }
        float bsv = bias[colg];
        float cs = 0.f, cq = 0.f;
        if (quad < 2) {  // rows quad*4+reg in 0..7 — this wave's valid rows
#pragma unroll
            for (int reg = 0; reg < 4; ++reg) {
                int r = row0 + quad * 4 + reg;
                if (r < N) {
                    long long off = (long long)r * D + colg;
                    float o = c[reg] + bsv;
                    if (residual) o += (float)h16in[off];
                    h16out[off] = (_Float16)o;
                    cs += o; cq += o * o;
                }
            }
        }
        csv[ct] = cs; cqv[ct] = cq;
    }

    // ---- BN-stat partials: cross-quad shfl reduction (padding quads contribute 0) ----
#pragma unroll
    for (int ct = 0; ct < 8; ++ct) {
        float s = csv[ct];
        s += __shfl_xor(s, 16);
        s += __shfl_xor(s, 32);
        float q = cqv[ct];
        q += __shfl_xor(q, 16);
        q += __shfl_xor(q, 32);
        if (quad == 0) {
            partial[(long long)tile * 256 + ct * 16 + ln] = s;
            partial[(long long)tile * 256 + 128 + ct * 16 + ln] = q;
        }
    }
}

// one block per graph: BN+relu, mean pool, linear head, sigmoid, blend with rf
__global__ void pool_head_kernel(const _Float16* __restrict__ h16, const float* __restrict__ aArr,
                                 const float* __restrict__ bArr, const int* __restrict__ gstart,
                                 const float* __restrict__ fw, const float* __restrict__ fb,
                                 const float* __restrict__ beta, const float* __restrict__ rf,
                                 float* __restrict__ out) {
    __shared__ float red[256];
    int g = blockIdx.x, t = threadIdx.x;
    int d = t & 127, half = t >> 7;
    int s0 = gstart[g], s1 = gstart[g + 1];
    float a = aArr[d], b = bArr[d];
    float acc = 0.f;
    for (int n = s0 + half; n < s1; n += 2)
        acc += fmaxf((float)h16[(long long)n * D + d] * a + b, 0.f);
    red[t] = acc;
    __syncthreads();
    if (t < 128) red[t] += red[t + 128];
    __syncthreads();
    if (t < 64) {
        float v = red[t] * fw[t] + red[t + 64] * fw[t + 64];
#pragma unroll
        for (int off = 32; off > 0; off >>= 1) v += __shfl_down(v, off);
        if (t == 0) {
            float c = fmaxf((float)(s1 - s0), 1.f);
            float pred = v / c + fb[0];
            float sig = 1.f / (1.f + __expf(-pred));
            float bb = beta[0];
            out[g] = (1.f - bb) * sig + bb * rf[g];
        }
    }
}

static inline size_t align16(size_t x) { return (x + 15) & ~(size_t)15; }

extern "C" void kernel_launch(void* const* d_in, const int* in_sizes, int n_in,
                              void* d_out, int out_size, void* d_ws, size_t ws_size,
                              hipStream_t stream) {
    const int* x = (const int*)d_in[0];
    const int* edge_index = (const int*)d_in[1];
    const int* edge_attr = (const int*)d_in[2];
    const int* batch = (const int*)d_in[3];
    const float* rf_pred = (const float*)d_in[4];
    const float* atom_emb = (const float*)d_in[5];
    const float* bond_emb = (const float*)d_in[6];
    const float* conv_w = (const float*)d_in[7];
    const float* conv_b = (const float*)d_in[8];
    const float* ts = (const float*)d_in[9];
    const float* gammas = (const float*)d_in[10];
    const float* bn_betas = (const float*)d_in[11];
    const float* final_w = (const float*)d_in[12];
    const float* final_b = (const float*)d_in[13];
    const float* beta = (const float*)d_in[14];
    float* out = (float*)d_out;

    int N = in_sizes[0] / 9;
    int E = in_sizes[1] / 2;
    int G = in_sizes[4];
    int L = in_sizes[9];

    int nTiles = (N + 7) / 8;
    size_t ND = (size_t)N * D;

    char* p = (char*)d_ws;
    _Float16* h16_a = (_Float16*)p;  p += align16(ND * 2);
    _Float16* h16_b = (_Float16*)p;  p += align16(ND * 2);
    __half2* evt = (__half2*)p;      p += align16((size_t)512 * 64 * 4);
    _Float16* wt = (_Float16*)p;     p += align16((size_t)L * 16384 * 2);
    float* partial = (float*)p;      p += align16((size_t)256 * nTiles * 4);
    float* aArr = (float*)p;         p += align16((size_t)D * 4);
    float* bArr = (float*)p;         p += align16((size_t)D * 4);
    int* gstart = (int*)p;           p += align16((size_t)(G + 1) * 4);
    int* deg = (int*)p;              p += align16((size_t)N * 4);
    int* row_start = (int*)p;        p += align16((size_t)(N + 1) * 4);
    int* cursor = (int*)p;           p += align16((size_t)N * 4);
    int* bsum = (int*)p;             p += align16((size_t)256 * 4);
    int2* csr = (int2*)p;            p += align16((size_t)E * 8);

    long long ndThreads = (long long)N * D;
    int ndBlocks = (int)((ndThreads + 255) / 256);
    int eBlocks = (E + 255) / 256;
    int nb1024 = (N + 1023) / 1024;
    int wtTotal = L * 16384;
    int miscTotal = 512 * 64 + wtTotal + N;
    int miscBlocks = (miscTotal + 255) / 256;
    int fusedBlocks = (nTiles + 1) / 2;
    float invN = 1.0f / (float)N;

    // ---- CSR + tables + graph boundaries ----
    (void)hipMemsetAsync(deg, 0, (size_t)N * sizeof(int), stream);
    hist_kernel<<<eBlocks, 256, 0, stream>>>(edge_index, deg, E);
    scanA_kernel<<<nb1024, 256, 0, stream>>>(deg, bsum, N);
    scanB_kernel<<<1, 256, 0, stream>>>(bsum, nb1024);
    scanC_kernel<<<nb1024, 256, 0, stream>>>(deg, bsum, row_start, cursor, N);
    scatter_kernel<<<eBlocks, 256, 0, stream>>>(edge_index, edge_attr, cursor, csr, E);
    misc_build_kernel<<<miscBlocks, 256, 0, stream>>>(bond_emb, evt, conv_w, wt, wtTotal,
                                                      batch, gstart, N, G);

    atom_embed_kernel<<<ndBlocks, 256, 0, stream>>>(x, atom_emb, h16_a, N);

    _Float16* h16c = h16_a;
    _Float16* h16n = h16_b;
    for (int l = 0; l < L; ++l) {
        int applyBN = (l >= 1) ? 1 : 0;
        if (applyBN) {
            bn_reduce_finalize_kernel<<<128, 256, 0, stream>>>(
                partial, nTiles, gammas + (size_t)(l - 1) * D,
                bn_betas + (size_t)(l - 1) * D, invN, aArr, bArr);
        }
        fused_layer_kernel<<<fusedBlocks, 128, 0, stream>>>(
            (const __half2*)h16c, aArr, bArr, applyBN, ts, l, row_start, csr, evt,
            wt + (size_t)l * 16384, conv_b + (size_t)l * D,
            applyBN, h16n, partial, nTiles, N);
        _Float16* tmp16 = h16c; h16c = h16n; h16n = tmp16;
    }

    bn_reduce_finalize_kernel<<<128, 256, 0, stream>>>(
        partial, nTiles, gammas + (size_t)(L - 1) * D,
        bn_betas + (size_t)(L - 1) * D, invN, aArr, bArr);
    pool_head_kernel<<<G, 256, 0, stream>>>(h16c, aArr, bArr, gstart,
                                            final_w, final_b, beta, rf_pred, out);
}

// Round 15
// 866.164 us; speedup vs baseline: 1.3729x; 1.3729x over previous
//
#include <hip/hip_runtime.h>
#include <hip/hip_fp16.h>
#include <math.h>

#define D 128
#define PF 12

typedef _Float16 f16x8 __attribute__((ext_vector_type(8)));
typedef _Float16 f16x2 __attribute__((ext_vector_type(2)));
typedef float f32x4_t __attribute__((ext_vector_type(4)));

static __device__ __forceinline__ f16x2 h2v(__half2 h) {
    union { __half2 h; f16x2 v; } u; u.h = h; return u.v;
}
static __device__ __forceinline__ __half2 v2h(f16x2 v) {
    union { f16x2 v; __half2 h; } u; u.v = v; return u.h;
}

// ---------------- CSR build (once per call; edge_index is layer-invariant) ----------------

__global__ void hist_kernel(const int* __restrict__ edge_index, int* __restrict__ deg, int E) {
    int e = blockIdx.x * blockDim.x + threadIdx.x;
    if (e >= E) return;
    atomicAdd(&deg[edge_index[E + e]], 1);
}

__global__ void scanA_kernel(const int* __restrict__ deg, int* __restrict__ bsum, int n) {
    __shared__ int red[256];
    int b = blockIdx.x, t = threadIdx.x;
    int base = b * 1024 + t * 4;
    int s = 0;
#pragma unroll
    for (int j = 0; j < 4; ++j)
        if (base + j < n) s += deg[base + j];
    red[t] = s;
    __syncthreads();
    for (int off = 128; off > 0; off >>= 1) {
        if (t < off) red[t] += red[t + off];
        __syncthreads();
    }
    if (t == 0) bsum[b] = red[0];
}

__global__ void scanB_kernel(int* __restrict__ bsum, int nb) {
    __shared__ int sh[256];
    int t = threadIdx.x;
    sh[t] = (t < nb) ? bsum[t] : 0;
    __syncthreads();
    for (int off = 1; off < 256; off <<= 1) {
        int v = (t >= off) ? sh[t - off] : 0;
        __syncthreads();
        sh[t] += v;
        __syncthreads();
    }
    if (t < nb) bsum[t] = (t == 0) ? 0 : sh[t - 1];
}

// writes row_start AND cursor (saves a d2d memcpy dispatch)
__global__ void scanC_kernel(const int* __restrict__ deg, const int* __restrict__ boff,
                             int* __restrict__ row_start, int* __restrict__ cursor, int n) {
    __shared__ int sh[256];
    int b = blockIdx.x, t = threadIdx.x;
    int base = b * 1024 + t * 4;
    int v[4];
#pragma unroll
    for (int j = 0; j < 4; ++j) v[j] = (base + j < n) ? deg[base + j] : 0;
    int p[4];
    p[0] = 0; p[1] = v[0]; p[2] = v[0] + v[1]; p[3] = v[0] + v[1] + v[2];
    int s = p[3] + v[3];
    sh[t] = s;
    __syncthreads();
    for (int off = 1; off < 256; off <<= 1) {
        int x = (t >= off) ? sh[t - off] : 0;
        __syncthreads();
        sh[t] += x;
        __syncthreads();
    }
    int off0 = boff[b] + sh[t] - s;
#pragma unroll
    for (int j = 0; j < 4; ++j)
        if (base + j < n) {
            row_start[base + j] = off0 + p[j];
            cursor[base + j] = off0 + p[j];
        }
    if (base <= n - 1 && n - 1 < base + 4) row_start[n] = off0 + s;
}

__global__ void scatter_kernel(const int* __restrict__ edge_index, const int* __restrict__ edge_attr,
                               int* __restrict__ cursor, int2* __restrict__ csr, int E) {
    int e = blockIdx.x * blockDim.x + threadIdx.x;
    if (e >= E) return;
    int src = edge_index[e];
    int dst = edge_index[E + e];
    int pos = atomicAdd(&cursor[dst], 1);
    int a0 = edge_attr[e * 3], a1 = edge_attr[e * 3 + 1], a2 = edge_attr[e * 3 + 2];
    csr[pos] = make_int2(src, a0 | (a1 << 3) | (a2 << 6));
}

// fused small setup: ev table (512 combos, half2) + Wt f16 transpose + gstart
__global__ void misc_build_kernel(const float* __restrict__ bond_emb, __half2* __restrict__ evt,
                                  const float* __restrict__ conv_w, _Float16* __restrict__ wt,
                                  int wtTotal, const int* __restrict__ batch,
                                  int* __restrict__ gstart, int N, int G) {
    int idx = blockIdx.x * blockDim.x + threadIdx.x;
    if (idx < 512 * 64) {
        int combo = idx >> 6, j = idx & 63;
        int d0 = 2 * j;
        float ex = bond_emb[(combo & 7) * D + d0] +
                   bond_emb[(8 + ((combo >> 3) & 7)) * D + d0] +
                   bond_emb[(16 + ((combo >> 6) & 7)) * D + d0];
        float ey = bond_emb[(combo & 7) * D + d0 + 1] +
                   bond_emb[(8 + ((combo >> 3) & 7)) * D + d0 + 1] +
                   bond_emb[(16 + ((combo >> 6) & 7)) * D + d0 + 1];
        evt[idx] = __floats2half2_rn(ex, ey);
        return;
    }
    int widx = idx - 512 * 64;
    if (widx < wtTotal) {
        int l = widx >> 14;
        int rem = widx & 16383;
        int n = rem >> 7, k = rem & 127;
        wt[widx] = (_Float16)conv_w[(l << 14) + k * 128 + n];
        return;
    }
    int n = widx - wtTotal;
    if (n >= N) return;
    if (n == 0) {
        for (int g = 0; g <= batch[0]; ++g) gstart[g] = 0;
    } else {
        int b0 = batch[n - 1], b1 = batch[n];
        for (int g = b0 + 1; g <= b1; ++g) gstart[g] = n;
    }
    if (n == N - 1) {
        for (int g = batch[N - 1] + 1; g <= G; ++g) gstart[g] = N;
    }
}

// ---------------- model kernels ----------------

// node state is f16-only
__global__ void atom_embed_kernel(const int* __restrict__ x,
                                  const float* __restrict__ atom_emb,
                                  _Float16* __restrict__ h16, int N) {
    long long idx = (long long)blockIdx.x * blockDim.x + threadIdx.x;
    if (idx >= (long long)N * D) return;
    int n = (int)(idx >> 7);
    int d = (int)(idx & 127);
    float acc = 0.f;
#pragma unroll
    for (int f = 0; f < 9; ++f) {
        int v = x[n * 9 + f];
        acc += atom_emb[(long long)(f * 64 + v) * D + d];
    }
    h16[idx] = (_Float16)acc;
}

// reduce per-tile column partials (layout partial[tile*256 + slot]) -> folded BN coeffs
__global__ void bn_reduce_finalize_kernel(const float* __restrict__ partial, int nb,
                                          const float* __restrict__ gamma,
                                          const float* __restrict__ bnbeta, float invN,
                                          float* __restrict__ aArr, float* __restrict__ bArr) {
    __shared__ float r1[256], r2[256];
    int d = blockIdx.x, t = threadIdx.x;
    float a1 = 0.f, a2 = 0.f;
    for (int i = t; i < nb; i += 256) {
        a1 += partial[(long long)i * 256 + d];
        a2 += partial[(long long)i * 256 + 128 + d];
    }
    r1[t] = a1; r2[t] = a2;
    __syncthreads();
    for (int off = 128; off > 0; off >>= 1) {
        if (t < off) { r1[t] += r1[t + off]; r2[t] += r2[t + off]; }
        __syncthreads();
    }
    if (t == 0) {
        float mean = r1[0] * invN;
        float var = r2[0] * invN - mean * mean;
        float a = rsqrtf(var + 1e-5f) * gamma[d];
        aArr[d] = a;
        bArr[d] = bnbeta[d] - mean * a;
    }
}

// R11 structure (the measured optimum of this design family — R12/R13/R14 barrier-free
// variants all regressed: per-wave fixed overhead + MFMA duplication cost more than the
// one barrier) + packed-f16 edge math (verified exact in R13/R14).
// Per-layer fused, 128 threads / 2 waves / 16-row tile: dst-centric softmax agg
// (f16 gathers, packed-f16 inline BN, 12-deep pipeline, double-buffered csr chunks
// [R10: FIFO vmcnt], register self rows, write-only row close) -> f16 y-tile in LDS
// -> ONE barrier -> column-split MFMA f16 16x128 @ 128x128 (+bias, +f16 residual,
// fp32 acc) -> f16 output + per-block BN-stat partials.
// segment-max skipped: softmax shift-invariant, msg bounded -> exp can't overflow fp32.
// NOTE (R9): NO global work-stealing counters on multi-XCD CDNA.
__global__ __launch_bounds__(128, 8) void fused_layer_kernel(
        const __half2* __restrict__ h16c,
        const float* __restrict__ aArr, const float* __restrict__ bArr, int applyBN,
        const float* __restrict__ ts, int l,
        const int* __restrict__ row_start, const int2* __restrict__ csr,
        const __half2* __restrict__ evt,
        const _Float16* __restrict__ wt, const float* __restrict__ bias,
        int residual, _Float16* __restrict__ h16out,
        float* __restrict__ partial, int N) {
    // y tile: 16 rows x 136 halves = 4352 B; stats scratch needs 8 KB -> size 8192
    __shared__ __align__(16) char smem[8192];
    _Float16* yh = (_Float16*)smem;
    __half2* tile2 = (__half2*)smem;  // half2 view: row stride 68

    int t = threadIdx.x;
    int row0 = blockIdx.x * 16;
    int wave = t >> 6;
    int lane = t & 63;
    float tsl = ts[l];
    int a = row0 + wave * 8;  // wave owns rows a..a+7

    f16x2 zerov = (f16x2)(_Float16)0;
    f16x2 bnA2 = zerov, bnB2 = zerov;
    if (applyBN) {
        float2 af = ((const float2*)aArr)[lane];
        float2 bf = ((const float2*)bArr)[lane];
        bnA2[0] = (_Float16)af.x; bnA2[1] = (_Float16)af.y;
        bnB2[0] = (_Float16)bf.x; bnB2[1] = (_Float16)bf.y;
    }
    __half2 zero2 = v2h(zerov);

    // issue rsv load, then 8 self-row gathers (FIFO vmcnt: readlane below waits only rsv)
    int rsv = row_start[min(a + min(lane, 8), N)];
    __half2 hsv0 = zero2, hsv1 = zero2, hsv2 = zero2, hsv3 = zero2;
    __half2 hsv4 = zero2, hsv5 = zero2, hsv6 = zero2, hsv7 = zero2;
    if (a + 0 < N) hsv0 = h16c[(size_t)(a + 0) * 64 + lane];
    if (a + 1 < N) hsv1 = h16c[(size_t)(a + 1) * 64 + lane];
    if (a + 2 < N) hsv2 = h16c[(size_t)(a + 2) * 64 + lane];
    if (a + 3 < N) hsv3 = h16c[(size_t)(a + 3) * 64 + lane];
    if (a + 4 < N) hsv4 = h16c[(size_t)(a + 4) * 64 + lane];
    if (a + 5 < N) hsv5 = h16c[(size_t)(a + 5) * 64 + lane];
    if (a + 6 < N) hsv6 = h16c[(size_t)(a + 6) * 64 + lane];
    if (a + 7 < N) hsv7 = h16c[(size_t)(a + 7) * 64 + lane];

    int s0 = __builtin_amdgcn_readlane(rsv, 0);
    int s1 = __builtin_amdgcn_readlane(rsv, 8);

    // double-buffered csr chunks: eaCur active, eaNxt in flight
    int c0 = s0;
    int2 eaCur = make_int2(0, 0), eaNxt = make_int2(0, 0);
    if (c0 + lane < s1) eaCur = csr[c0 + lane];
    if (c0 + 64 + lane < s1) eaNxt = csr[c0 + 64 + lane];

    __half2 hvS[PF], evS[PF];
#pragma unroll
    for (int k = 0; k < PF; ++k) {
        int pp = s0 + k;
        if (pp < s1) {  // q = k < 64: always chunk 0
            int srcp = __builtin_amdgcn_readlane(eaCur.x, k);
            int cbp = __builtin_amdgcn_readlane(eaCur.y, k);
            hvS[k] = h16c[(size_t)srcp * 64 + lane];
            evS[k] = evt[(size_t)cbp * 64 + lane];
        }
    }

    float accwx = 0.f, accwy = 0.f, accmx = 0.f, accmy = 0.f;
    int cur = 0;
    int nend = __builtin_amdgcn_readlane(rsv, 1);

#define CLOSE_ROW()                                                           \
    {                                                                         \
        __half2 hh;                                                           \
        switch (cur) {                                                        \
            case 0: hh = hsv0; break; case 1: hh = hsv1; break;               \
            case 2: hh = hsv2; break; case 3: hh = hsv3; break;               \
            case 4: hh = hsv4; break; case 5: hh = hsv5; break;               \
            case 6: hh = hsv6; break; default: hh = hsv7; break;              \
        }                                                                     \
        f16x2 hvv = h2v(hh);                                                  \
        if (applyBN)                                                          \
            hvv = __builtin_elementwise_max(hvv * bnA2 + bnB2, zerov);        \
        float2 yy;                                                            \
        yy.x = (float)hvv[0] + accmx / (accwx + 1e-16f);                      \
        yy.y = (float)hvv[1] + accmy / (accwy + 1e-16f);                      \
        tile2[(wave * 8 + cur) * 68 + lane] = __floats2half2_rn(yy.x, yy.y);  \
        accwx = accwy = accmx = accmy = 0.f;                                  \
        cur++;                                                                \
        nend = __builtin_amdgcn_readlane(rsv, min(cur + 1, 8));               \
    }

    while (cur < 8 && nend == s0) CLOSE_ROW();  // leading empty rows

    int total = s1 - s0;
    for (int it = 0; it < total; it += PF) {
#pragma unroll
        for (int k = 0; k < PF; ++k) {
            int p = s0 + it + k;
            if (p < s1) {
                f16x2 hv2 = h2v(hvS[k]);
                if (applyBN)
                    hv2 = __builtin_elementwise_max(hv2 * bnA2 + bnB2, zerov);
                f16x2 m2 = __builtin_elementwise_max(hv2 + h2v(evS[k]), zerov);
                float mx = (float)m2[0] + 1e-7f;
                float my = (float)m2[1] + 1e-7f;
                float wx = __expf(mx * tsl);
                float wy = __expf(my * tsl);
                accwx += wx; accmx = fmaf(wx, mx, accmx);
                accwy += wy; accmy = fmaf(wy, my, accmy);
                int pp = p + PF;
                if (pp < s1) {
                    if (pp >= c0 + 64) {  // rollover: eaNxt loaded ~64 edges ago, no drain
                        c0 += 64;
                        eaCur = eaNxt;
                        eaNxt = make_int2(0, 0);
                        if (c0 + 64 + lane < s1) eaNxt = csr[c0 + 64 + lane];
                    }
                    int q = pp - c0;
                    int srcp = __builtin_amdgcn_readlane(eaCur.x, q);
                    int cbp = __builtin_amdgcn_readlane(eaCur.y, q);
                    hvS[k] = h16c[(size_t)srcp * 64 + lane];
                    evS[k] = evt[(size_t)cbp * 64 + lane];
                }
                while (cur < 8 && nend == p + 1) CLOSE_ROW();
            }
        }
    }
#undef CLOSE_ROW
    __syncthreads();

    // ---- MFMA matmul: both waves read all 16 tile rows; wave w covers cols w*64.. ----
    int ln = t & 15;
    int quad = (t & 63) >> 4;
    const _Float16* h16in = (const _Float16*)h16c;

    float cs[4] = {0.f, 0.f, 0.f, 0.f};
    float cq[4] = {0.f, 0.f, 0.f, 0.f};
    const _Float16* ap = yh + ln * 136 + quad * 8;
#pragma unroll
    for (int ct = 0; ct < 4; ++ct) {
        int colg = (wave * 4 + ct) * 16 + ln;
        const _Float16* bp = wt + (size_t)colg * 128 + quad * 8;
        f32x4_t c = {0.f, 0.f, 0.f, 0.f};
#pragma unroll
        for (int kk = 0; kk < 4; ++kk) {
            f16x8 av = *(const f16x8*)(ap + kk * 32);
            f16x8 bv = *(const f16x8*)(bp + kk * 32);
            c = __builtin_amdgcn_mfma_f32_16x16x32_f16(av, bv, c, 0, 0, 0);
        }
        float bsv = bias[colg];
#pragma unroll
        for (int reg = 0; reg < 4; ++reg) {
            int r = row0 + quad * 4 + reg;
            if (r < N) {
                long long off = (long long)r * D + colg;
                float o = c[reg] + bsv;
                if (residual) o += (float)h16in[off];
                h16out[off] = (_Float16)o;
                cs[ct] += o; cq[ct] += o * o;
            }
        }
    }

    // ---- BN-stat partials (reuse smem; y tile dead) ----
    __syncthreads();
    float* stats = (float*)smem;
    int grp = wave * 4 + quad;  // 0..7
#pragma unroll
    for (int ct = 0; ct < 4; ++ct) {
        int colg = (wave * 4 + ct) * 16 + ln;
        stats[grp * 256 + colg] = cs[ct];
        stats[grp * 256 + 128 + colg] = cq[ct];
    }
    __syncthreads();
    float ssumA = 0.f, ssumB = 0.f;
#pragma unroll
    for (int g = 0; g < 8; ++g) {
        ssumA += stats[g * 256 + t];
        ssumB += stats[g * 256 + 128 + t];
    }
    partial[(long long)blockIdx.x * 256 + t] = ssumA;
    partial[(long long)blockIdx.x * 256 + 128 + t] = ssumB;
}

// one block per graph: BN+relu, mean pool, linear head, sigmoid, blend with rf
__global__ void pool_head_kernel(const _Float16* __restrict__ h16, const float* __restrict__ aArr,
                                 const float* __restrict__ bArr, const int* __restrict__ gstart,
                                 const float* __restrict__ fw, const float* __restrict__ fb,
                                 const float* __restrict__ beta, const float* __restrict__ rf,
                                 float* __restrict__ out) {
    __shared__ float red[256];
    int g = blockIdx.x, t = threadIdx.x;
    int d = t & 127, half = t >> 7;
    int s0 = gstart[g], s1 = gstart[g + 1];
    float a = aArr[d], b = bArr[d];
    float acc = 0.f;
    for (int n = s0 + half; n < s1; n += 2)
        acc += fmaxf((float)h16[(long long)n * D + d] * a + b, 0.f);
    red[t] = acc;
    __syncthreads();
    if (t < 128) red[t] += red[t + 128];
    __syncthreads();
    if (t < 64) {
        float v = red[t] * fw[t] + red[t + 64] * fw[t + 64];
#pragma unroll
        for (int off = 32; off > 0; off >>= 1) v += __shfl_down(v, off);
        if (t == 0) {
            float c = fmaxf((float)(s1 - s0), 1.f);
            float pred = v / c + fb[0];
            float sig = 1.f / (1.f + __expf(-pred));
            float bb = beta[0];
            out[g] = (1.f - bb) * sig + bb * rf[g];
        }
    }
}

static inline size_t align16(size_t x) { return (x + 15) & ~(size_t)15; }

extern "C" void kernel_launch(void* const* d_in, const int* in_sizes, int n_in,
                              void* d_out, int out_size, void* d_ws, size_t ws_size,
                              hipStream_t stream) {
    const int* x = (const int*)d_in[0];
    const int* edge_index = (const int*)d_in[1];
    const int* edge_attr = (const int*)d_in[2];
    const int* batch = (const int*)d_in[3];
    const float* rf_pred = (const float*)d_in[4];
    const float* atom_emb = (const float*)d_in[5];
    const float* bond_emb = (const float*)d_in[6];
    const float* conv_w = (const float*)d_in[7];
    const float* conv_b = (const float*)d_in[8];
    const float* ts = (const float*)d_in[9];
    const float* gammas = (const float*)d_in[10];
    const float* bn_betas = (const float*)d_in[11];
    const float* final_w = (const float*)d_in[12];
    const float* final_b = (const float*)d_in[13];
    const float* beta = (const float*)d_in[14];
    float* out = (float*)d_out;

    int N = in_sizes[0] / 9;
    int E = in_sizes[1] / 2;
    int G = in_sizes[4];
    int L = in_sizes[9];

    int nTiles = (N + 15) / 16;
    size_t ND = (size_t)N * D;

    char* p = (char*)d_ws;
    _Float16* h16_a = (_Float16*)p;  p += align16(ND * 2);
    _Float16* h16_b = (_Float16*)p;  p += align16(ND * 2);
    __half2* evt = (__half2*)p;      p += align16((size_t)512 * 64 * 4);
    _Float16* wt = (_Float16*)p;     p += align16((size_t)L * 16384 * 2);
    float* partial = (float*)p;      p += align16((size_t)256 * nTiles * 4);
    float* aArr = (float*)p;         p += align16((size_t)D * 4);
    float* bArr = (float*)p;         p += align16((size_t)D * 4);
    int* gstart = (int*)p;           p += align16((size_t)(G + 1) * 4);
    int* deg = (int*)p;              p += align16((size_t)N * 4);
    int* row_start = (int*)p;        p += align16((size_t)(N + 1) * 4);
    int* cursor = (int*)p;           p += align16((size_t)N * 4);
    int* bsum = (int*)p;             p += align16((size_t)256 * 4);
    int2* csr = (int2*)p;            p += align16((size_t)E * 8);

    long long ndThreads = (long long)N * D;
    int ndBlocks = (int)((ndThreads + 255) / 256);
    int eBlocks = (E + 255) / 256;
    int nb1024 = (N + 1023) / 1024;
    int wtTotal = L * 16384;
    int miscTotal = 512 * 64 + wtTotal + N;
    int miscBlocks = (miscTotal + 255) / 256;
    float invN = 1.0f / (float)N;

    // ---- CSR + tables + graph boundaries ----
    (void)hipMemsetAsync(deg, 0, (size_t)N * sizeof(int), stream);
    hist_kernel<<<eBlocks, 256, 0, stream>>>(edge_index, deg, E);
    scanA_kernel<<<nb1024, 256, 0, stream>>>(deg, bsum, N);
    scanB_kernel<<<1, 256, 0, stream>>>(bsum, nb1024);
    scanC_kernel<<<nb1024, 256, 0, stream>>>(deg, bsum, row_start, cursor, N);
    scatter_kernel<<<eBlocks, 256, 0, stream>>>(edge_index, edge_attr, cursor, csr, E);
    misc_build_kernel<<<miscBlocks, 256, 0, stream>>>(bond_emb, evt, conv_w, wt, wtTotal,
                                                      batch, gstart, N, G);

    atom_embed_kernel<<<ndBlocks, 256, 0, stream>>>(x, atom_emb, h16_a, N);

    _Float16* h16c = h16_a;
    _Float16* h16n = h16_b;
    for (int l = 0; l < L; ++l) {
        int applyBN = (l >= 1) ? 1 : 0;
        if (applyBN) {
            bn_reduce_finalize_kernel<<<128, 256, 0, stream>>>(
                partial, nTiles, gammas + (size_t)(l - 1) * D,
                bn_betas + (size_t)(l - 1) * D, invN, aArr, bArr);
        }
        fused_layer_kernel<<<nTiles, 128, 0, stream>>>(
            (const __half2*)h16c, aArr, bArr, applyBN, ts, l, row_start, csr, evt,
            wt + (size_t)l * 16384, conv_b + (size_t)l * D,
            applyBN, h16n, partial, N);
        _Float16* tmp16 = h16c; h16c = h16n; h16n = tmp16;
    }

    bn_reduce_finalize_kernel<<<128, 256, 0, stream>>>(
        partial, nTiles, gammas + (size_t)(L - 1) * D,
        bn_betas + (size_t)(L - 1) * D, invN, aArr, bArr);
    pool_head_kernel<<<G, 256, 0, stream>>>(h16c, aArr, bArr, gstart,
                                            final_w, final_b, beta, rf_pred, out);
}